// Round 7
// baseline (53.142 us; speedup 1.0000x reference)
//
#include <hip/hip_runtime.h>
#include <math.h>
#include <type_traits>

#define QDEPTH 10
#define WIRES 10
#define NSTATE 1024
#define NGATES (QDEPTH * WIRES)

typedef float f2 __attribute__((ext_vector_type(2)));

// ---------------------------------------------------------------------------
// Layout: 1024 blocks x 128 thr (2 waves); each block simulates 2 elements.
// Stored index s = w<<9 | j<<6 | lane  (w: wave bit, j: 3 reg bits, lane: 6).
// Wire q <-> bit (9-q): wire 0 -> wave bit (folded into CNOT gather);
// wires 1-3 -> reg bits 2..0; wires 4-9 -> lane bits 5..0 (shfl_xor).
// LDS: interleaved f2 amp at pair-index swz(s) = s ^ ((s>>5)&31) (<=2-way).
// ---------------------------------------------------------------------------
constexpr unsigned sigma_apply(int q, int r, unsigned i) {
    int cb = 9 - q, tb = 9 - ((q + r) % 10);
    return i ^ (((i >> cb) & 1u) << tb);
}
constexpr unsigned G_apply(int l, unsigned i) {
    int r = (l % 9) + 1;
    for (int q = 9; q >= 0; --q) i = sigma_apply(q, r, i);  // G = s0∘s1∘…∘s9
    return i;
}
constexpr unsigned swz(unsigned w) { return w ^ ((w >> 5) & 31u); }

struct U4 { unsigned a, b, c, d; };          // 8 packed u16 gather targets
struct P8 { U4 t[QDEPTH][128]; };
constexpr P8 make_perm8() {
    P8 p{};
    for (int l = 0; l < QDEPTH; ++l)
        for (unsigned wl = 0; wl < 128; ++wl) {
            unsigned w = wl >> 6, lane = wl & 63u;
            unsigned t[8];
            for (unsigned j = 0; j < 8; ++j)
                t[j] = swz(G_apply(l, (w << 9) | (j << 6) | lane));
            p.t[l][wl].a = t[0] | (t[1] << 16);
            p.t[l][wl].b = t[2] | (t[3] << 16);
            p.t[l][wl].c = t[4] | (t[5] << 16);
            p.t[l][wl].d = t[6] | (t[7] << 16);
        }
    return p;
}
__constant__ P8 PERM8 = make_perm8();

template <int N, int I = 0, typename F>
__device__ __forceinline__ void static_for(F&& f) {
    if constexpr (I < N) {
        f(std::integral_constant<int, I>{});
        static_for<N, I + 1>(f);
    }
}

__device__ __forceinline__ float fxor(float a, unsigned s) {
    return __uint_as_float(__float_as_uint(a) ^ s);
}
__device__ __forceinline__ f2 fxor2(f2 a, unsigned s) {
    f2 r; r.x = fxor(a.x, s); r.y = fxor(a.y, s); return r;
}
__device__ __forceinline__ f2 swap2(f2 a) { return __builtin_shufflevector(a, a, 1, 0); }
__device__ __forceinline__ f2 pkfma(f2 a, f2 b, f2 c) {
    return __builtin_elementwise_fma(a, b, c);
}

// ---------------------------------------------------------------------------
// Kernel 1: 100 Rot gates -> packed coefficient pairs per gate (8 floats):
// (Ar,Ar), (-Ai,Ai), (Br,Br), (-Bi,Bi)   [SU(2): rows differ by negation only]
// ---------------------------------------------------------------------------
__global__ void gates_kernel(const float* __restrict__ w, float* __restrict__ g) {
    int i = threadIdx.x;
    if (i >= NGATES) return;
    float phi = tanhf(w[3 * i + 0]);
    float th  = tanhf(w[3 * i + 1]);
    float om  = tanhf(w[3 * i + 2]);
    float c = cosf(0.5f * th), s = sinf(0.5f * th);
    float a = 0.5f * (phi + om), d = 0.5f * (phi - om);
    float Ar =  cosf(a) * c, Ai = -sinf(a) * c;    // g00
    float Br = -cosf(d) * s, Bi = -sinf(d) * s;    // g01
    float* p = g + 8 * i;
    p[0] = Ar;  p[1] = Ar;
    p[2] = -Ai; p[3] = Ai;
    p[4] = Br;  p[5] = Br;
    p[6] = -Bi; p[7] = Bi;
}

// Reg-bit gate on an 8-register state: 4 static pairs, pure pk-FMA.
template <int JB>
__device__ __forceinline__ void apply_gate_reg(f2 (&s)[8], const f2* __restrict__ gp) {
    const f2 ArP = gp[0], AiSW = gp[1], BrP = gp[2], BiSW = gp[3];
    static_for<4>([&](auto P) {
        constexpr int p  = P.value;
        constexpr int lo = p & ((1 << JB) - 1);
        constexpr int j  = ((p & ~((1 << JB) - 1)) << 1) | lo;
        constexpr int jp = j | (1 << JB);
        f2 a = s[j], b = s[jp];
        f2 as = swap2(a), bs = swap2(b);
        f2 n0 = a * ArP;                 // row0: A*a + B*b
        n0 = pkfma(AiSW, as, n0);
        n0 = pkfma(BrP,  b,  n0);
        n0 = pkfma(BiSW, bs, n0);
        f2 n1 = a * (-BrP);              // row1: -conj(B)*a + conj(A)*b
        n1 = pkfma(BiSW,  as, n1);
        n1 = pkfma(ArP,   b,  n1);
        n1 = pkfma(-AiSW, bs, n1);
        s[j] = n0; s[jp] = n1;
    });
}

// ---------------------------------------------------------------------------
// Kernel 2: 2 waves x 2 batch elements per block; 8+8 packed amps per thread.
// One barrier per layer; all control overhead shared between the 2 elements.
// ---------------------------------------------------------------------------
__global__ __launch_bounds__(128) void sim_kernel(const float* __restrict__ x,
                                                  const float* __restrict__ gtab,
                                                  float* __restrict__ out) {
    __shared__ f2 buf[2][2][NSTATE];     // [parity][elem][swz-idx], 32 KB
    __shared__ f2 glds[NGATES * 4];      // packed gate records, 3.2 KB
    __shared__ float wsum[2][2];         // [elem][wave]
    const int tid  = threadIdx.x;
    const int w    = tid >> 6;
    const int lane = tid & 63;
    const int whi  = w << 9;
    const float* xA = x + (size_t)(2 * blockIdx.x + 0) * NSTATE;
    const float* xB = x + (size_t)(2 * blockIdx.x + 1) * NSTATE;

    // stage gate records once
    for (int i = tid; i < NGATES * 4; i += 128)
        glds[i] = ((const f2*)gtab)[i];

    f2 sA[8], sB[8];

    // ---- amplitude embedding + cross-wave L2 normalize (both elements) ----
    float ssA = 0.f, ssB = 0.f;
    static_for<8>([&](auto J) {
        constexpr int j = J.value;
        float vA = xA[whi | (j << 6) | lane];
        float vB = xB[whi | (j << 6) | lane];
        sA[j].x = vA; sA[j].y = 0.f;
        sB[j].x = vB; sB[j].y = 0.f;
        ssA = fmaf(vA, vA, ssA);
        ssB = fmaf(vB, vB, ssB);
    });
#pragma unroll
    for (int off = 1; off < 64; off <<= 1) {
        ssA += __shfl_xor(ssA, off);
        ssB += __shfl_xor(ssB, off);
    }
    if (lane == 0) { wsum[0][w] = ssA; wsum[1][w] = ssB; }
    __syncthreads();
    const float nA = 1.0f / sqrtf(wsum[0][0] + wsum[0][1]);
    const float nB = 1.0f / sqrtf(wsum[1][0] + wsum[1][1]);
    static_for<8>([&](auto J) { sA[J.value] *= nA; sB[J.value] *= nB; });

#pragma unroll 1
    for (int l = 0; l < QDEPTH; ++l) {
        f2* bA = buf[l & 1][0];
        f2* bB = buf[l & 1][1];
        const f2* gl = glds + 40 * l;

        // prefetch packed gather targets (shared by both elements)
        const U4 e = PERM8.t[l][tid];
        unsigned tarr[8] = { e.a & 0xFFFFu, e.a >> 16, e.b & 0xFFFFu, e.b >> 16,
                             e.c & 0xFFFFu, e.c >> 16, e.d & 0xFFFFu, e.d >> 16 };

        // ---- wires 1,2,3 on reg bits 2,1,0 (pure pk-FMA) ----
        apply_gate_reg<2>(sA, gl + 4 * 1);  apply_gate_reg<2>(sB, gl + 4 * 1);
        apply_gate_reg<1>(sA, gl + 4 * 2);  apply_gate_reg<1>(sB, gl + 4 * 2);
        apply_gate_reg<0>(sA, gl + 4 * 3);  apply_gate_reg<0>(sB, gl + 4 * 3);

        // ---- wires 4..9 on lane bits 5..0 (shuffles; A/B chains interleave) ----
        static_for<6>([&](auto Q) {
            constexpr int qq = Q.value;               // wire 4+qq
            constexpr int m  = 1 << (5 - qq);
            const f2* gp = gl + 4 * (4 + qq);
            const f2 ArP = gp[0], BiSW = gp[3];
            const unsigned sm = (lane & m) ? 0x80000000u : 0u;
            const f2 c2 = fxor2(gp[1], sm);           // ±AiSW
            const f2 c3 = fxor2(gp[2], sm);           // ±BrP
            static_for<8>([&](auto J) {
                constexpr int j = J.value;
                f2 a = sA[j], b = sB[j];
                f2 pa, pb;
                pa.x = __shfl_xor(a.x, m); pa.y = __shfl_xor(a.y, m);
                pb.x = __shfl_xor(b.x, m); pb.y = __shfl_xor(b.y, m);
                f2 na = a * ArP, nb = b * ArP;
                na = pkfma(c2, swap2(a), na);   nb = pkfma(c2, swap2(b), nb);
                na = pkfma(c3, pa, na);         nb = pkfma(c3, pb, nb);
                na = pkfma(BiSW, swap2(pa), na); nb = pkfma(BiSW, swap2(pb), nb);
                sA[j] = na; sB[j] = nb;
            });
        });

        // ---- write both states to LDS (b64, swizzled; <=2-way) ----
        static_for<8>([&](auto J) {
            constexpr int j = J.value;
            int si = whi | (j << 6) | lane;
            int a  = si ^ ((si >> 5) & 31);
            bA[a] = sA[j]; bB[a] = sB[j];
        });
        __syncthreads();

        // ---- wire 0 (bit 9) folded into CNOT gather (shared addressing) ----
        const float Ar = gl[0].x, Ai = gl[1].y, Br = gl[2].x, Bi = gl[3].y;
        static_for<8>([&](auto J) {
            constexpr int j = J.value;
            unsigned t0 = tarr[j];
            unsigned t1 = t0 ^ 528u;                  // swz(p^512)
            unsigned sg = (t0 & 512u) << 22;          // bit9 -> sign bit
            float Ais = fxor(Ai, sg), Brs = fxor(Br, sg);
            f2 v0 = bA[t0], v1 = bA[t1];
            f2 u0 = bB[t0], u1 = bB[t1];
            f2 n, u;
            n.x = fmaf(Ar, v0.x, fmaf(-Ais, v0.y, fmaf(Brs, v1.x, -Bi * v1.y)));
            n.y = fmaf(Ar, v0.y, fmaf( Ais, v0.x, fmaf(Brs, v1.y,  Bi * v1.x)));
            u.x = fmaf(Ar, u0.x, fmaf(-Ais, u0.y, fmaf(Brs, u1.x, -Bi * u1.y)));
            u.y = fmaf(Ar, u0.y, fmaf( Ais, u0.x, fmaf(Brs, u1.y,  Bi * u1.x)));
            sA[j] = n; sB[j] = u;
        });
        // no trailing barrier: next layer writes the other parity buffer
    }

    // ---- probs = clip(|amp|^2 * 1024, 0, 1); layout already logical ----
    float* oA = out + (size_t)(2 * blockIdx.x + 0) * NSTATE;
    float* oB = out + (size_t)(2 * blockIdx.x + 1) * NSTATE;
    static_for<8>([&](auto J) {
        constexpr int j = J.value;
        float pA = fmaf(sA[j].x, sA[j].x, sA[j].y * sA[j].y) * (float)NSTATE;
        float pB = fmaf(sB[j].x, sB[j].x, sB[j].y * sB[j].y) * (float)NSTATE;
        oA[whi | (j << 6) | lane] = fminf(pA, 1.0f);
        oB[whi | (j << 6) | lane] = fminf(pB, 1.0f);
    });
}

extern "C" void kernel_launch(void* const* d_in, const int* in_sizes, int n_in,
                              void* d_out, int out_size, void* d_ws, size_t ws_size,
                              hipStream_t stream) {
    const float* x = (const float*)d_in[0];   // [1024,1,32,32] f32
    const float* w = (const float*)d_in[1];   // [10,10,3] f32
    float* out   = (float*)d_out;             // [1024,1,32,32] f32
    float* gates = (float*)d_ws;              // 100*8 floats scratch

    gates_kernel<<<1, 128, 0, stream>>>(w, gates);
    sim_kernel<<<512, 128, 0, stream>>>(x, gates, out);
}

// Round 8
// 40.029 us; speedup vs baseline: 1.3276x; 1.3276x over previous
//
#include <hip/hip_runtime.h>
#include <math.h>
#include <type_traits>

#define QDEPTH 10
#define WIRES 10
#define NSTATE 1024
#define NGATES (QDEPTH * WIRES)

typedef float f2 __attribute__((ext_vector_type(2)));
typedef float f4 __attribute__((ext_vector_type(4)));

// ---------------------------------------------------------------------------
// Layout: 1 wave = 1 batch element. Stored index s = j<<6 | lane (j: 4 reg
// bits 9..6, lane: 6 bits 5..0). Wire q <-> stored bit (9-q):
//   bits 9..6 (wires 0-3): register gates (pure pk-FMA)
//   bit 5 (wire 4): permlane32_swap   bit 4 (wire 5): permlane16_swap
//   bit 3 (wire 6): DPP row_ror:8    bits 1,0 (wires 8,9): DPP quad_perm
//   bit 2 (wire 7): folded into the per-layer CNOT gather (one b128 read)
// LDS write layout A(p) = ((p>>3)<<3)|((p&3)<<1)|bit2(p): {p,p^4} adjacent,
// so fold partners arrive in one 16B read. Zero barriers; wave-synchronous.
// ---------------------------------------------------------------------------
constexpr unsigned sigma_apply(int q, int r, unsigned i) {
    int cb = 9 - q, tb = 9 - ((q + r) % 10);
    return i ^ (((i >> cb) & 1u) << tb);
}
constexpr unsigned G_apply(int l, unsigned i) {
    int r = (l % 9) + 1;
    for (int q = 9; q >= 0; --q) i = sigma_apply(q, r, i);  // G = s0∘s1∘…∘s9
    return i;
}

struct FoldT { unsigned short e[QDEPTH][64][16]; };
constexpr FoldT make_fold() {
    FoldT t{};
    for (int l = 0; l < QDEPTH; ++l)
        for (unsigned lane = 0; lane < 64; ++lane)
            for (unsigned j = 0; j < 16; ++j) {
                unsigned s = (j << 6) | lane;
                unsigned h = G_apply(l, s);          // pre-CNOT source index
                unsigned d = h & ~4u;                // pair base (bit2 = 0)
                unsigned a_half = ((d >> 3) << 2) | (d & 3u);   // A(d)>>1, 9 bits
                t.e[l][lane][j] = (unsigned short)(a_half | (((h >> 2) & 1u) << 15));
            }
    return t;
}
__constant__ FoldT FOLD = make_fold();

template <int N, int I = 0, typename F>
__device__ __forceinline__ void static_for(F&& f) {
    if constexpr (I < N) {
        f(std::integral_constant<int, I>{});
        static_for<N, I + 1>(f);
    }
}

__device__ __forceinline__ float fxor(float a, unsigned s) {
    return __uint_as_float(__float_as_uint(a) ^ s);
}
__device__ __forceinline__ f2 fxor2(f2 a, unsigned s) {
    f2 r; r.x = fxor(a.x, s); r.y = fxor(a.y, s); return r;
}
__device__ __forceinline__ f2 swap2(f2 a) { return __builtin_shufflevector(a, a, 1, 0); }
__device__ __forceinline__ f2 pkfma(f2 a, f2 b, f2 c) {
    return __builtin_elementwise_fma(a, b, c);
}

// ---------------------------------------------------------------------------
// Kernel 1: 100 Rot gates -> packed records (Ar,Ar)(-Ai,Ai)(Br,Br)(-Bi,Bi).
// ---------------------------------------------------------------------------
__global__ void gates_kernel(const float* __restrict__ w, float* __restrict__ g) {
    int i = threadIdx.x;
    if (i >= NGATES) return;
    float phi = tanhf(w[3 * i + 0]);
    float th  = tanhf(w[3 * i + 1]);
    float om  = tanhf(w[3 * i + 2]);
    float c = cosf(0.5f * th), s = sinf(0.5f * th);
    float a = 0.5f * (phi + om), d = 0.5f * (phi - om);
    float Ar =  cosf(a) * c, Ai = -sinf(a) * c;    // g00
    float Br = -cosf(d) * s, Bi = -sinf(d) * s;    // g01
    float* p = g + 8 * i;
    p[0] = Ar;  p[1] = Ar;
    p[2] = -Ai; p[3] = Ai;
    p[4] = Br;  p[5] = Br;
    p[6] = -Bi; p[7] = Bi;
}

// Register gate on j-bit JB: 8 static pairs, uniform-sign pk-FMA (r6-proven).
template <int JB>
__device__ __forceinline__ void apply_gate_reg(f2 (&s)[16], f2 ArP, f2 AiSW,
                                               f2 BrP, f2 BiSW) {
    static_for<8>([&](auto P) {
        constexpr int p  = P.value;
        constexpr int lo = p & ((1 << JB) - 1);
        constexpr int j  = ((p & ~((1 << JB) - 1)) << 1) | lo;
        constexpr int jp = j | (1 << JB);
        f2 a = s[j], b = s[jp];
        f2 as = swap2(a), bs = swap2(b);
        f2 n0 = a * ArP;
        n0 = pkfma(AiSW, as, n0); n0 = pkfma(BrP, b, n0); n0 = pkfma(BiSW, bs, n0);
        f2 n1 = a * (-BrP);
        n1 = pkfma(BiSW, as, n1); n1 = pkfma(ArP, b, n1); n1 = pkfma(-AiSW, bs, n1);
        s[j] = n0; s[jp] = n1;
    });
}

// Lane gate on bit 5 (xor32) or bit 4 (xor16) via permlane swap:
// interleave -> the gate becomes a uniform register-pair gate -> de-interleave.
template <bool IS32>
__device__ __forceinline__ void plane_gate(f2& v, f2& w, f2 ArP, f2 AiSW,
                                           f2 BrP, f2 BiSW) {
    unsigned vx = __float_as_uint(v.x), vy = __float_as_uint(v.y);
    unsigned wx = __float_as_uint(w.x), wy = __float_as_uint(w.y);
    unsigned Xx, Xy, Yx, Yy;
    if constexpr (IS32) {
        auto rx = __builtin_amdgcn_permlane32_swap(vx, wx, false, false);
        auto ry = __builtin_amdgcn_permlane32_swap(vy, wy, false, false);
        Xx = rx[0]; Yx = rx[1]; Xy = ry[0]; Yy = ry[1];
    } else {
        auto rx = __builtin_amdgcn_permlane16_swap(vx, wx, false, false);
        auto ry = __builtin_amdgcn_permlane16_swap(vy, wy, false, false);
        Xx = rx[0]; Yx = rx[1]; Xy = ry[0]; Yy = ry[1];
    }
    f2 X, Y;
    X.x = __uint_as_float(Xx); X.y = __uint_as_float(Xy);
    Y.x = __uint_as_float(Yx); Y.y = __uint_as_float(Yy);
    f2 as = swap2(X), bs = swap2(Y);
    f2 n0 = X * ArP;
    n0 = pkfma(AiSW, as, n0); n0 = pkfma(BrP, Y, n0); n0 = pkfma(BiSW, bs, n0);
    f2 n1 = X * (-BrP);
    n1 = pkfma(BiSW, as, n1); n1 = pkfma(ArP, Y, n1); n1 = pkfma(-AiSW, bs, n1);
    unsigned ax = __float_as_uint(n0.x), ay = __float_as_uint(n0.y);
    unsigned bx = __float_as_uint(n1.x), by = __float_as_uint(n1.y);
    if constexpr (IS32) {
        auto ox = __builtin_amdgcn_permlane32_swap(ax, bx, false, false);
        auto oy = __builtin_amdgcn_permlane32_swap(ay, by, false, false);
        v.x = __uint_as_float(ox[0]); v.y = __uint_as_float(oy[0]);
        w.x = __uint_as_float(ox[1]); w.y = __uint_as_float(oy[1]);
    } else {
        auto ox = __builtin_amdgcn_permlane16_swap(ax, bx, false, false);
        auto oy = __builtin_amdgcn_permlane16_swap(ay, by, false, false);
        v.x = __uint_as_float(ox[0]); v.y = __uint_as_float(oy[0]);
        w.x = __uint_as_float(ox[1]); w.y = __uint_as_float(oy[1]);
    }
}

// DPP cross-lane xor within a 16-row: CTRL = quad_perm/row_ror encoding.
template <int CTRL>
__device__ __forceinline__ f2 dpp2(f2 v) {
    f2 r;
    r.x = __uint_as_float((unsigned)__builtin_amdgcn_mov_dpp(
              (int)__float_as_uint(v.x), CTRL, 0xf, 0xf, true));
    r.y = __uint_as_float((unsigned)__builtin_amdgcn_mov_dpp(
              (int)__float_as_uint(v.y), CTRL, 0xf, 0xf, true));
    return r;
}

// Lane gate via DPP partner + per-lane signs (r6-proven formula).
template <int CTRL, int M>
__device__ __forceinline__ void dpp_gate(f2 (&s)[16], int lane, f2 ArP, f2 AiSW,
                                         f2 BrP, f2 BiSW) {
    const unsigned sm = (lane & M) ? 0x80000000u : 0u;
    const f2 c2 = fxor2(AiSW, sm);
    const f2 c3 = fxor2(BrP, sm);
    static_for<16>([&](auto J) {
        constexpr int j = J.value;
        f2 a = s[j];
        f2 p = dpp2<CTRL>(a);
        f2 n = a * ArP;
        n = pkfma(c2, swap2(a), n);
        n = pkfma(c3, p, n);
        n = pkfma(BiSW, swap2(p), n);
        s[j] = n;
    });
}

// ---------------------------------------------------------------------------
// Kernel 2: 256 blocks x 256 thr = 1024 waves; 1 wave = 1 element; 16 f2/thr.
// Zero barriers; one LDS round-trip per layer (write b64 x16, read b128 x16).
// ---------------------------------------------------------------------------
__global__ __launch_bounds__(256) void sim_kernel(const float* __restrict__ x,
                                                  const float* __restrict__ gtab,
                                                  float* __restrict__ out) {
    __shared__ f2 amps[4][NSTATE];       // per-wave private regions, 32 KB
    const int tid  = threadIdx.x;
    const int w    = tid >> 6;
    const int lane = tid & 63;
    const int elem = blockIdx.x * 4 + w;
    const float* xb = x + (size_t)elem * NSTATE;
    f2* myb = amps[w];
    const f2* gt = (const f2*)gtab;

    f2 s[16];

    // ---- amplitude embedding + per-wave L2 normalize ----
    float ss = 0.f;
    static_for<16>([&](auto J) {
        constexpr int j = J.value;
        float v = xb[(j << 6) | lane];
        s[j].x = v; s[j].y = 0.f;
        ss = fmaf(v, v, ss);
    });
#pragma unroll
    for (int off = 1; off < 64; off <<= 1) ss += __shfl_xor(ss, off);
    const float nrm = 1.0f / sqrtf(ss);
    static_for<16>([&](auto J) { s[J.value] *= nrm; });

    // write-address base: A(p) = (j<<6) | wb
    const int wb = ((lane >> 3) << 3) | ((lane & 3) << 1) | ((lane >> 2) & 1);

#pragma unroll 1
    for (int l = 0; l < QDEPTH; ++l) {
        const f2* gl = gt + 40 * l;

        // prefetch fold-table entries (32B per thread, coalesced)
        const uint4* tp = (const uint4*)&FOLD.e[l][lane][0];
        uint4 e0 = tp[0], e1 = tp[1];
        unsigned ew[8] = { e0.x, e0.y, e0.z, e0.w, e1.x, e1.y, e1.z, e1.w };

        // ---- wires 0..3 on reg bits 9..6 ----
        apply_gate_reg<3>(s, gl[0],  gl[1],  gl[2],  gl[3]);
        apply_gate_reg<2>(s, gl[4],  gl[5],  gl[6],  gl[7]);
        apply_gate_reg<1>(s, gl[8],  gl[9],  gl[10], gl[11]);
        apply_gate_reg<0>(s, gl[12], gl[13], gl[14], gl[15]);

        // ---- wire 4 (bit 5, xor32) / wire 5 (bit 4, xor16) via permlane ----
        {
            f2 a0 = gl[16], a1 = gl[17], a2 = gl[18], a3 = gl[19];
            static_for<8>([&](auto K) {
                constexpr int k = K.value;
                plane_gate<true>(s[2 * k], s[2 * k + 1], a0, a1, a2, a3);
            });
        }
        {
            f2 a0 = gl[20], a1 = gl[21], a2 = gl[22], a3 = gl[23];
            static_for<8>([&](auto K) {
                constexpr int k = K.value;
                plane_gate<false>(s[2 * k], s[2 * k + 1], a0, a1, a2, a3);
            });
        }

        // ---- wire 6 (bit 3, xor8 = row_ror:8); wires 8,9 (quad_perm) ----
        dpp_gate<0x128, 8>(s, lane, gl[24], gl[25], gl[26], gl[27]);
        dpp_gate<0x04E, 2>(s, lane, gl[32], gl[33], gl[34], gl[35]);
        dpp_gate<0x0B1, 1>(s, lane, gl[36], gl[37], gl[38], gl[39]);

        // ---- write state (grouped so {p, p^4} are adjacent) ----
        static_for<16>([&](auto J) {
            constexpr int j = J.value;
            myb[(j << 6) | wb] = s[j];
        });

        // ---- wire 7 (bit 2) folded into CNOT gather: one b128 per amp ----
        {
            const f2 ArP = gl[28], AiSW = gl[29], BrP = gl[30], BiSW = gl[31];
            static_for<16>([&](auto J) {
                constexpr int j = J.value;
                unsigned E  = (j & 1) ? (ew[j >> 1] >> 16) : (ew[j >> 1] & 0xFFFFu);
                unsigned sm = (E & 0x8000u) << 16;         // h2 -> sign bit
                const f4 pv = *(const f4*)&myb[(E & 0x1FFu) << 1];
                f2 v0; v0.x = pv.x; v0.y = pv.y;           // bit2 = 0 source
                f2 v1; v1.x = pv.z; v1.y = pv.w;           // bit2 = 1 source
                bool h2 = (E & 0x8000u) != 0;
                f2 a  = h2 ? v1 : v0;                      // self
                f2 pp = h2 ? v0 : v1;                      // partner
                f2 c2 = fxor2(AiSW, sm);
                f2 c3 = fxor2(BrP, sm);
                f2 n = a * ArP;
                n = pkfma(c2, swap2(a), n);
                n = pkfma(c3, pp, n);
                n = pkfma(BiSW, swap2(pp), n);
                s[j] = n;
            });
        }
    }

    // ---- probs = clip(|amp|^2 * 1024, 0, 1); identity layout ----
    float* ob = out + (size_t)elem * NSTATE;
    static_for<16>([&](auto J) {
        constexpr int j = J.value;
        float p = fmaf(s[j].x, s[j].x, s[j].y * s[j].y) * (float)NSTATE;
        ob[(j << 6) | lane] = fminf(p, 1.0f);
    });
}

extern "C" void kernel_launch(void* const* d_in, const int* in_sizes, int n_in,
                              void* d_out, int out_size, void* d_ws, size_t ws_size,
                              hipStream_t stream) {
    const float* x = (const float*)d_in[0];   // [1024,1,32,32] f32
    const float* w = (const float*)d_in[1];   // [10,10,3] f32
    float* out   = (float*)d_out;             // [1024,1,32,32] f32
    float* gates = (float*)d_ws;              // 100*8 floats scratch

    gates_kernel<<<1, 128, 0, stream>>>(w, gates);
    sim_kernel<<<256, 256, 0, stream>>>(x, gates, out);
}